// Round 1
// baseline (598.517 us; speedup 1.0000x reference)
//
#include <hip/hip_runtime.h>
#include <math.h>

#define BB 8
#define PP 57744
#define NOBJ 20
#define CC 81
#define ROWS (BB*PP)

// ws layout in 4-byte units
#define W_CNT  0      // [0]=num_pos [1]=sl1_sum [2]=pos_ce [3]=neg_ce [4]=neg_cnt [5]=eqCtr [8]=prefix [9]=Kr [10]=T [11]=eqSlots
#define W_HIST 64     // 4*256 bins
#define W_BP   1088   // 160 ints
#define W_CONF 2048           // ROWS ints
#define W_KEY  (2048 + ROWS)  // ROWS uints
#define W_CE   (2048 + 2*ROWS)// ROWS floats

__device__ __forceinline__ unsigned keymap(float f) {
    unsigned u = __float_as_uint(f);
    return (u & 0x80000000u) ? ~u : (u | 0x80000000u);
}

__device__ __forceinline__ float smooth_l1(float d) {
    float a = fabsf(d);
    return a < 1.f ? 0.5f * d * d : a - 0.5f;
}

// One block per (gt object, batch): argmax over all priors of IoU, tie -> lowest prior idx.
__global__ void k_best_prior(const float* __restrict__ priors,
                             const float* __restrict__ gt,
                             int* __restrict__ bp) {
    int n = blockIdx.x, b = blockIdx.y;
    const float* t = gt + (b * NOBJ + n) * 4;
    float tx1 = t[0], ty1 = t[1], tx2 = t[2], ty2 = t[3];
    float ta = (tx2 - tx1) * (ty2 - ty1);
    float best = -1.0f; int bestp = 0;
    for (int p = threadIdx.x; p < PP; p += 256) {
        float4 pr = ((const float4*)priors)[p];
        float px1 = pr.x - pr.z * 0.5f, py1 = pr.y - pr.w * 0.5f;
        float px2 = pr.x + pr.z * 0.5f, py2 = pr.y + pr.w * 0.5f;
        float iw = fmaxf(fminf(tx2, px2) - fmaxf(tx1, px1), 0.f);
        float ih = fmaxf(fminf(ty2, py2) - fmaxf(ty1, py1), 0.f);
        float inter = iw * ih;
        float iou = inter / (ta + (px2 - px1) * (py2 - py1) - inter);
        if (iou > best) { best = iou; bestp = p; }  // strict >: lowest p wins ties
    }
    __shared__ float sov[256]; __shared__ int spi[256];
    int tid = threadIdx.x;
    sov[tid] = best; spi[tid] = bestp; __syncthreads();
    for (int s = 128; s > 0; s >>= 1) {
        if (tid < s) {
            if (sov[tid + s] > sov[tid] ||
                (sov[tid + s] == sov[tid] && spi[tid + s] < spi[tid])) {
                sov[tid] = sov[tid + s]; spi[tid] = spi[tid + s];
            }
        }
        __syncthreads();
    }
    if (tid == 0) bp[b * NOBJ + n] = spi[0];
}

// Per prior: best truth (argmax over 20, tie->first), force-match (last gt wins),
// conf_t, and smooth-L1 loc loss for positives.
__global__ void k_match(const float* __restrict__ loc_data,
                        const float* __restrict__ priors,
                        const float* __restrict__ gt,
                        const int* __restrict__ labels,
                        const int* __restrict__ bp,
                        int* __restrict__ conf_t,
                        float* __restrict__ cnt_f,
                        int* __restrict__ cnt_i) {
    int b = blockIdx.y;
    int tid = threadIdx.x;
    int p = blockIdx.x * 256 + tid;
    __shared__ float st[NOBJ][4];
    __shared__ int slab[NOBJ], sbp[NOBJ];
    if (tid < NOBJ * 4) ((float*)st)[tid] = gt[b * NOBJ * 4 + tid];
    if (tid < NOBJ) { slab[tid] = labels[b * NOBJ + tid]; sbp[tid] = bp[b * NOBJ + tid]; }
    __syncthreads();
    float s_l1 = 0.f; int is_pos = 0;
    if (p < PP) {
        float4 pr = ((const float4*)priors)[p];
        float px1 = pr.x - pr.z * 0.5f, py1 = pr.y - pr.w * 0.5f;
        float px2 = pr.x + pr.z * 0.5f, py2 = pr.y + pr.w * 0.5f;
        float pa = (px2 - px1) * (py2 - py1);
        float best = -1.f; int bn = 0;
        for (int n = 0; n < NOBJ; n++) {
            float tx1 = st[n][0], ty1 = st[n][1], tx2 = st[n][2], ty2 = st[n][3];
            float iw = fmaxf(fminf(tx2, px2) - fmaxf(tx1, px1), 0.f);
            float ih = fmaxf(fminf(ty2, py2) - fmaxf(ty1, py1), 0.f);
            float inter = iw * ih;
            float iou = inter / ((tx2 - tx1) * (ty2 - ty1) + pa - inter);
            if (iou > best) { best = iou; bn = n; }  // tie -> first n
        }
        float ov = best;
        for (int n = 0; n < NOBJ; n++)
            if (sbp[n] == p) { bn = n; ov = 2.0f; }  // last n wins
        int conf = slab[bn];
        if (ov < 0.5f) conf = -1;
        if (ov < 0.4f) conf = 0;
        conf_t[b * PP + p] = conf;
        if (conf > 0) {
            is_pos = 1;
            float mx1 = st[bn][0], my1 = st[bn][1], mx2 = st[bn][2], my2 = st[bn][3];
            float gcx = ((mx1 + mx2) * 0.5f - pr.x) / (0.1f * pr.z);
            float gcy = ((my1 + my2) * 0.5f - pr.y) / (0.1f * pr.w);
            float gw = logf((mx2 - mx1) / pr.z) / 0.2f;
            float gh = logf((my2 - my1) / pr.w) / 0.2f;
            float4 ld = ((const float4*)loc_data)[b * PP + p];
            s_l1 = smooth_l1(ld.x - gcx) + smooth_l1(ld.y - gcy) +
                   smooth_l1(ld.z - gw) + smooth_l1(ld.w - gh);
        }
    }
    __shared__ float rs[256]; __shared__ int rc[256];
    rs[tid] = s_l1; rc[tid] = is_pos; __syncthreads();
    for (int s = 128; s > 0; s >>= 1) {
        if (tid < s) { rs[tid] += rs[tid + s]; rc[tid] += rc[tid + s]; }
        __syncthreads();
    }
    if (tid == 0) {
        if (rs[0] != 0.f) atomicAdd(&cnt_f[1], rs[0]);
        if (rc[0])        atomicAdd(&cnt_i[0], rc[0]);
    }
}

// One wave per 81-class row: logsumexp, CE at target, fg-max score key.
__global__ void __launch_bounds__(256) k_conf(const float* __restrict__ conf_data,
                                              const int* __restrict__ conf_t,
                                              unsigned* __restrict__ key,
                                              float* __restrict__ ce,
                                              float* __restrict__ cnt_f) {
    int w = threadIdx.x >> 6, lane = threadIdx.x & 63;
    int row = blockIdx.x * 4 + w;               // ROWS % 4 == 0
    const float* x = conf_data + (size_t)row * CC;
    float x1 = x[lane];                          // lanes 0..63 all < 81
    int c2 = lane + 64;
    float x2 = (c2 < CC) ? x[c2] : -INFINITY;
    float m = fmaxf(x1, x2);
    for (int o = 32; o > 0; o >>= 1) m = fmaxf(m, __shfl_xor(m, o, 64));
    float fg = fmaxf((lane >= 1) ? x1 : -INFINITY, x2);  // classes 1..80
    for (int o = 32; o > 0; o >>= 1) fg = fmaxf(fg, __shfl_xor(fg, o, 64));
    float e = expf(x1 - m) + ((c2 < CC) ? expf(x2 - m) : 0.f);
    for (int o = 32; o > 0; o >>= 1) e += __shfl_xor(e, o, 64);
    float lse = m + logf(e);
    int ct = conf_t[row];
    int ctc = min(max(ct, 0), CC - 1);
    float xct = (lane == ctc) ? x1 : ((c2 == ctc) ? x2 : -INFINITY);
    for (int o = 32; o > 0; o >>= 1) xct = fmaxf(xct, __shfl_xor(xct, o, 64));
    float cev = lse - xct;
    if (lane == 0) {
        ce[row] = cev;
        key[row] = (ct == 0) ? keymap(fg) : 0u;  // non-candidates -> smallest key
        if (ct > 0) atomicAdd(&cnt_f[2], cev);
    }
}

// Radix-select pass s (8-bit digits, MSB first) histogram.
__global__ void k_hist(const unsigned* __restrict__ key,
                       unsigned* __restrict__ hist,
                       const int* __restrict__ cnt, int s) {
    __shared__ unsigned lh[256];
    int tid = threadIdx.x;
    lh[tid] = 0; __syncthreads();
    unsigned prefix = (s == 0) ? 0u : (unsigned)cnt[8];
    int shift = 24 - 8 * s;
    for (int r = blockIdx.x * 256 + tid; r < ROWS; r += gridDim.x * 256) {
        unsigned k = key[r];
        if (s == 0 || (k >> (shift + 8)) == prefix)
            atomicAdd(&lh[(k >> shift) & 0xffu], 1u);
    }
    __syncthreads();
    if (lh[tid]) atomicAdd(&hist[s * 256 + tid], lh[tid]);
}

// Pick the digit where the descending cumulative count crosses Kr.
__global__ void k_scan(const unsigned* __restrict__ hist, int* __restrict__ cnt, int s) {
    __shared__ unsigned sd[256];
    int i = threadIdx.x;
    sd[i] = hist[s * 256 + i];
    __syncthreads();
    for (int off = 1; off < 256; off <<= 1) {
        unsigned add = (i + off < 256) ? sd[i + off] : 0u;
        __syncthreads();
        sd[i] += add;
        __syncthreads();
    }
    unsigned Kr, prefix;
    if (s == 0) { Kr = 3u * (unsigned)cnt[0]; prefix = 0u; }
    else        { prefix = (unsigned)cnt[8]; Kr = (unsigned)cnt[9]; }
    unsigned cum = sd[i];
    unsigned upper = (i < 255) ? sd[i + 1] : 0u;
    bool sel = (upper < Kr) && (cum >= Kr || i == 0);
    if (sel) {
        unsigned np = (prefix << 8) | (unsigned)i;
        unsigned nKr = Kr - upper;
        if (s < 3) { cnt[8] = (int)np; cnt[9] = (int)nKr; }
        else       { cnt[10] = (int)np; cnt[11] = (int)nKr; }
    }
}

// Sum CE over selected negatives (key > T, or == T up to eqSlots).
__global__ void k_negsum(const unsigned* __restrict__ key,
                         const float* __restrict__ ce,
                         const int* __restrict__ conf_t,
                         int* __restrict__ cnt_i,
                         float* __restrict__ cnt_f) {
    int tid = threadIdx.x;
    int r = blockIdx.x * 256 + tid;
    float s = 0.f; int c = 0;
    unsigned T = (unsigned)cnt_i[10];
    int eqS = cnt_i[11];
    if (r < ROWS && conf_t[r] == 0) {
        unsigned k = key[r];
        bool sel = false;
        if (k > T) sel = true;
        else if (k == T) { int slot = atomicAdd(&cnt_i[5], 1); sel = slot < eqS; }
        if (sel) { s = ce[r]; c = 1; }
    }
    __shared__ float rs[256]; __shared__ int rc[256];
    rs[tid] = s; rc[tid] = c; __syncthreads();
    for (int st = 128; st > 0; st >>= 1) {
        if (tid < st) { rs[tid] += rs[tid + st]; rc[tid] += rc[tid + st]; }
        __syncthreads();
    }
    if (tid == 0) {
        if (rs[0] != 0.f) atomicAdd(&cnt_f[3], rs[0]);
        if (rc[0])        atomicAdd(&cnt_i[4], rc[0]);
    }
}

__global__ void k_final(const int* __restrict__ cnt_i,
                        const float* __restrict__ cnt_f,
                        float* __restrict__ out) {
    int np = cnt_i[0], nn = cnt_i[4];
    out[0] = cnt_f[1] / (float)max(np, 1);
    out[1] = (cnt_f[2] + cnt_f[3]) / (float)max(np + nn, 1);
}

extern "C" void kernel_launch(void* const* d_in, const int* in_sizes, int n_in,
                              void* d_out, int out_size, void* d_ws, size_t ws_size,
                              hipStream_t stream) {
    const float* loc    = (const float*)d_in[0];
    const float* conf   = (const float*)d_in[1];
    const float* priors = (const float*)d_in[2];
    const float* gt     = (const float*)d_in[3];
    const int*   labels = (const int*)d_in[4];
    float* out = (float*)d_out;
    int*      wi = (int*)d_ws;
    float*    wf = (float*)d_ws;
    unsigned* wu = (unsigned*)d_ws;

    hipMemsetAsync(d_ws, 0, 8192, stream);  // counters + hists + bp
    k_best_prior<<<dim3(NOBJ, BB), 256, 0, stream>>>(priors, gt, wi + W_BP);
    k_match<<<dim3((PP + 255) / 256, BB), 256, 0, stream>>>(
        loc, priors, gt, labels, wi + W_BP, wi + W_CONF, wf, wi);
    k_conf<<<ROWS / 4, 256, 0, stream>>>(conf, wi + W_CONF, wu + W_KEY, wf + W_CE, wf);
    for (int s = 0; s < 4; s++) {
        k_hist<<<512, 256, 0, stream>>>(wu + W_KEY, wu + W_HIST, wi, s);
        k_scan<<<1, 256, 0, stream>>>(wu + W_HIST, wi, s);
    }
    k_negsum<<<(ROWS + 255) / 256, 256, 0, stream>>>(
        wu + W_KEY, wf + W_CE, wi + W_CONF, wi, wf);
    k_final<<<1, 1, 0, stream>>>(wi, wf, out);
}

// Round 2
// 472.173 us; speedup vs baseline: 1.2676x; 1.2676x over previous
//
#include <hip/hip_runtime.h>
#include <math.h>

#define BB 8
#define PP 57744
#define NOBJ 20
#define CC 81
#define ROWS (BB*PP)
#define RPB 64        // rows per block in k_conf
#define BPSPLIT 16    // prior-scan splits in k_best_prior
#define BPCHUNK ((PP + BPSPLIT - 1) / BPSPLIT)   // 3609

// ws layout in 4-byte units
#define W_CNT  0      // [0]=num_pos [1]=sl1_sum [2]=pos_ce [3]=neg_ce [4]=neg_cnt [5]=eqCtr [8]=prefix [9]=Kr [10]=T [11]=eqSlots
#define W_HIST 64     // 4*256 bins
#define W_BP   1088   // 160 u64 (byte offset 4352, 8-aligned)
#define W_CONF 2048           // ROWS ints
#define W_KEY  (2048 + ROWS)  // ROWS uints
#define W_CE   (2048 + 2*ROWS)// ROWS floats

__device__ __forceinline__ unsigned keymap(float f) {
    unsigned u = __float_as_uint(f);
    return (u & 0x80000000u) ? ~u : (u | 0x80000000u);
}

__device__ __forceinline__ float smooth_l1(float d) {
    float a = fabsf(d);
    return a < 1.f ? 0.5f * d * d : a - 0.5f;
}

// Grid (NOBJ, BB, BPSPLIT): per-(gt,batch) argmax over a prior chunk, packed
// (iou_bits<<32)|(~p) so u64 max == (max iou, lowest prior idx). IoU >= 0 so
// raw float bits are order-preserving.
__global__ void k_best_prior(const float* __restrict__ priors,
                             const float* __restrict__ gt,
                             unsigned long long* __restrict__ bp) {
    int n = blockIdx.x, b = blockIdx.y;
    int p0 = blockIdx.z * BPCHUNK;
    int p1 = min(p0 + BPCHUNK, PP);
    const float* t = gt + (b * NOBJ + n) * 4;
    float tx1 = t[0], ty1 = t[1], tx2 = t[2], ty2 = t[3];
    float ta = (tx2 - tx1) * (ty2 - ty1);
    unsigned long long best = 0ull;
    for (int p = p0 + threadIdx.x; p < p1; p += 256) {
        float4 pr = ((const float4*)priors)[p];
        float px1 = pr.x - pr.z * 0.5f, py1 = pr.y - pr.w * 0.5f;
        float px2 = pr.x + pr.z * 0.5f, py2 = pr.y + pr.w * 0.5f;
        float iw = fmaxf(fminf(tx2, px2) - fmaxf(tx1, px1), 0.f);
        float ih = fmaxf(fminf(ty2, py2) - fmaxf(ty1, py1), 0.f);
        float inter = iw * ih;
        float iou = inter / (ta + (px2 - px1) * (py2 - py1) - inter);
        unsigned long long pk = ((unsigned long long)__float_as_uint(iou) << 32)
                              | (unsigned long long)(0xFFFFFFFFu - (unsigned)p);
        if (pk > best) best = pk;
    }
    __shared__ unsigned long long sb[256];
    int tid = threadIdx.x;
    sb[tid] = best; __syncthreads();
    for (int s = 128; s > 0; s >>= 1) {
        if (tid < s && sb[tid + s] > sb[tid]) sb[tid] = sb[tid + s];
        __syncthreads();
    }
    if (tid == 0) atomicMax(&bp[b * NOBJ + n], sb[0]);
}

// Per prior: best truth (argmax over 20, tie->first), force-match (last gt wins),
// conf_t, and smooth-L1 loc loss for positives.
__global__ void k_match(const float* __restrict__ loc_data,
                        const float* __restrict__ priors,
                        const float* __restrict__ gt,
                        const int* __restrict__ labels,
                        const unsigned long long* __restrict__ bp,
                        int* __restrict__ conf_t,
                        float* __restrict__ cnt_f,
                        int* __restrict__ cnt_i) {
    int b = blockIdx.y;
    int tid = threadIdx.x;
    int p = blockIdx.x * 256 + tid;
    __shared__ float st[NOBJ][4];
    __shared__ int slab[NOBJ], sbp[NOBJ];
    if (tid < NOBJ * 4) ((float*)st)[tid] = gt[b * NOBJ * 4 + tid];
    if (tid < NOBJ) {
        slab[tid] = labels[b * NOBJ + tid];
        sbp[tid] = (int)(0xFFFFFFFFu - (unsigned)bp[b * NOBJ + tid]);
    }
    __syncthreads();
    float s_l1 = 0.f; int is_pos = 0;
    if (p < PP) {
        float4 pr = ((const float4*)priors)[p];
        float px1 = pr.x - pr.z * 0.5f, py1 = pr.y - pr.w * 0.5f;
        float px2 = pr.x + pr.z * 0.5f, py2 = pr.y + pr.w * 0.5f;
        float pa = (px2 - px1) * (py2 - py1);
        float best = -1.f; int bn = 0;
        for (int n = 0; n < NOBJ; n++) {
            float tx1 = st[n][0], ty1 = st[n][1], tx2 = st[n][2], ty2 = st[n][3];
            float iw = fmaxf(fminf(tx2, px2) - fmaxf(tx1, px1), 0.f);
            float ih = fmaxf(fminf(ty2, py2) - fmaxf(ty1, py1), 0.f);
            float inter = iw * ih;
            float iou = inter / ((tx2 - tx1) * (ty2 - ty1) + pa - inter);
            if (iou > best) { best = iou; bn = n; }  // tie -> first n
        }
        float ov = best;
        for (int n = 0; n < NOBJ; n++)
            if (sbp[n] == p) { bn = n; ov = 2.0f; }  // last n wins
        int conf = slab[bn];
        if (ov < 0.5f) conf = -1;
        if (ov < 0.4f) conf = 0;
        conf_t[b * PP + p] = conf;
        if (conf > 0) {
            is_pos = 1;
            float mx1 = st[bn][0], my1 = st[bn][1], mx2 = st[bn][2], my2 = st[bn][3];
            float gcx = ((mx1 + mx2) * 0.5f - pr.x) / (0.1f * pr.z);
            float gcy = ((my1 + my2) * 0.5f - pr.y) / (0.1f * pr.w);
            float gw = logf((mx2 - mx1) / pr.z) / 0.2f;
            float gh = logf((my2 - my1) / pr.w) / 0.2f;
            float4 ld = ((const float4*)loc_data)[b * PP + p];
            s_l1 = smooth_l1(ld.x - gcx) + smooth_l1(ld.y - gcy) +
                   smooth_l1(ld.z - gw) + smooth_l1(ld.w - gh);
        }
    }
    __shared__ float rs[256]; __shared__ int rc[256];
    rs[tid] = s_l1; rc[tid] = is_pos; __syncthreads();
    for (int s = 128; s > 0; s >>= 1) {
        if (tid < s) { rs[tid] += rs[tid + s]; rc[tid] += rc[tid + s]; }
        __syncthreads();
    }
    if (tid == 0) {
        if (rs[0] != 0.f) atomicAdd(&cnt_f[1], rs[0]);
        if (rc[0])        atomicAdd(&cnt_i[0], rc[0]);
    }
}

// 64 rows per block staged via coalesced float4 -> LDS; 4 threads/row serial
// scan with native exp2/log2. 7218 blocks * 5184 floats == ROWS*81 exactly.
__global__ void __launch_bounds__(256) k_conf(const float* __restrict__ conf_data,
                                              const int* __restrict__ conf_t,
                                              unsigned* __restrict__ key,
                                              float* __restrict__ ce,
                                              float* __restrict__ cnt_f) {
    __shared__ float sx[RPB * CC];   // 20736 B
    int tid = threadIdx.x;
    const float4* g = (const float4*)(conf_data + (size_t)blockIdx.x * (RPB * CC));
    float4* s4 = (float4*)sx;
    #pragma unroll
    for (int i = 0; i < 5; i++) s4[tid + 256 * i] = g[tid + 256 * i];
    if (tid < (RPB * CC / 4) - 1280) s4[1280 + tid] = g[1280 + tid];
    __syncthreads();

    int r = tid >> 2, t = tid & 3;
    int row = blockIdx.x * RPB + r;
    const float* x = sx + r * CC;

    float m = (t == 0) ? x[0] : -INFINITY;
    float fg = -INFINITY;
    for (int c = (t == 0) ? 4 : t; c < CC; c += 4) {
        float v = x[c];
        m = fmaxf(m, v);
        fg = fmaxf(fg, v);
    }
    m = fmaxf(m, __shfl_xor(m, 1));
    m = fmaxf(m, __shfl_xor(m, 2));
    fg = fmaxf(fg, __shfl_xor(fg, 1));
    fg = fmaxf(fg, __shfl_xor(fg, 2));

    const float LOG2E = 1.4426950408889634f;
    float e = 0.f;
    for (int c = t; c < CC; c += 4) e += exp2f((x[c] - m) * LOG2E);
    e += __shfl_xor(e, 1);
    e += __shfl_xor(e, 2);

    if (t == 0) {
        float lse = m + log2f(e) * 0.6931471805599453f;
        int ct = conf_t[row];
        int ctc = min(max(ct, 0), CC - 1);
        float cev = lse - x[ctc];
        ce[row] = cev;
        key[row] = (ct == 0) ? keymap(fg) : 0u;
        if (ct > 0) atomicAdd(&cnt_f[2], cev);
    }
}

// Radix-select pass s (8-bit digits, MSB first) histogram.
__global__ void k_hist(const unsigned* __restrict__ key,
                       unsigned* __restrict__ hist,
                       const int* __restrict__ cnt, int s) {
    __shared__ unsigned lh[256];
    int tid = threadIdx.x;
    lh[tid] = 0; __syncthreads();
    unsigned prefix = (s == 0) ? 0u : (unsigned)cnt[8];
    int shift = 24 - 8 * s;
    for (int r = blockIdx.x * 256 + tid; r < ROWS; r += gridDim.x * 256) {
        unsigned k = key[r];
        if (s == 0 || (k >> (shift + 8)) == prefix)
            atomicAdd(&lh[(k >> shift) & 0xffu], 1u);
    }
    __syncthreads();
    if (lh[tid]) atomicAdd(&hist[s * 256 + tid], lh[tid]);
}

// Pick the digit where the descending cumulative count crosses Kr.
__global__ void k_scan(const unsigned* __restrict__ hist, int* __restrict__ cnt, int s) {
    __shared__ unsigned sd[256];
    int i = threadIdx.x;
    sd[i] = hist[s * 256 + i];
    __syncthreads();
    for (int off = 1; off < 256; off <<= 1) {
        unsigned add = (i + off < 256) ? sd[i + off] : 0u;
        __syncthreads();
        sd[i] += add;
        __syncthreads();
    }
    unsigned Kr, prefix;
    if (s == 0) { Kr = 3u * (unsigned)cnt[0]; prefix = 0u; }
    else        { prefix = (unsigned)cnt[8]; Kr = (unsigned)cnt[9]; }
    unsigned cum = sd[i];
    unsigned upper = (i < 255) ? sd[i + 1] : 0u;
    bool sel = (upper < Kr) && (cum >= Kr || i == 0);
    if (sel) {
        unsigned np = (prefix << 8) | (unsigned)i;
        unsigned nKr = Kr - upper;
        if (s < 3) { cnt[8] = (int)np; cnt[9] = (int)nKr; }
        else       { cnt[10] = (int)np; cnt[11] = (int)nKr; }
    }
}

// Sum CE over selected negatives (key > T, or == T up to eqSlots).
__global__ void k_negsum(const unsigned* __restrict__ key,
                         const float* __restrict__ ce,
                         const int* __restrict__ conf_t,
                         int* __restrict__ cnt_i,
                         float* __restrict__ cnt_f) {
    int tid = threadIdx.x;
    int r = blockIdx.x * 256 + tid;
    float s = 0.f; int c = 0;
    unsigned T = (unsigned)cnt_i[10];
    int eqS = cnt_i[11];
    if (r < ROWS && conf_t[r] == 0) {
        unsigned k = key[r];
        bool sel = false;
        if (k > T) sel = true;
        else if (k == T) { int slot = atomicAdd(&cnt_i[5], 1); sel = slot < eqS; }
        if (sel) { s = ce[r]; c = 1; }
    }
    __shared__ float rs[256]; __shared__ int rc[256];
    rs[tid] = s; rc[tid] = c; __syncthreads();
    for (int st = 128; st > 0; st >>= 1) {
        if (tid < st) { rs[tid] += rs[tid + st]; rc[tid] += rc[tid + st]; }
        __syncthreads();
    }
    if (tid == 0) {
        if (rs[0] != 0.f) atomicAdd(&cnt_f[3], rs[0]);
        if (rc[0])        atomicAdd(&cnt_i[4], rc[0]);
    }
}

__global__ void k_final(const int* __restrict__ cnt_i,
                        const float* __restrict__ cnt_f,
                        float* __restrict__ out) {
    int np = cnt_i[0], nn = cnt_i[4];
    out[0] = cnt_f[1] / (float)max(np, 1);
    out[1] = (cnt_f[2] + cnt_f[3]) / (float)max(np + nn, 1);
}

extern "C" void kernel_launch(void* const* d_in, const int* in_sizes, int n_in,
                              void* d_out, int out_size, void* d_ws, size_t ws_size,
                              hipStream_t stream) {
    const float* loc    = (const float*)d_in[0];
    const float* conf   = (const float*)d_in[1];
    const float* priors = (const float*)d_in[2];
    const float* gt     = (const float*)d_in[3];
    const int*   labels = (const int*)d_in[4];
    float* out = (float*)d_out;
    int*      wi = (int*)d_ws;
    float*    wf = (float*)d_ws;
    unsigned* wu = (unsigned*)d_ws;
    unsigned long long* wbp = (unsigned long long*)(wi + W_BP);

    hipMemsetAsync(d_ws, 0, 8192, stream);  // counters + hists + bp
    k_best_prior<<<dim3(NOBJ, BB, BPSPLIT), 256, 0, stream>>>(priors, gt, wbp);
    k_match<<<dim3((PP + 255) / 256, BB), 256, 0, stream>>>(
        loc, priors, gt, labels, wbp, wi + W_CONF, wf, wi);
    k_conf<<<ROWS / RPB, 256, 0, stream>>>(conf, wi + W_CONF, wu + W_KEY, wf + W_CE, wf);
    for (int s = 0; s < 4; s++) {
        k_hist<<<512, 256, 0, stream>>>(wu + W_KEY, wu + W_HIST, wi, s);
        k_scan<<<1, 256, 0, stream>>>(wu + W_HIST, wi, s);
    }
    k_negsum<<<(ROWS + 255) / 256, 256, 0, stream>>>(
        wu + W_KEY, wf + W_CE, wi + W_CONF, wi, wf);
    k_final<<<1, 1, 0, stream>>>(wi, wf, out);
}